// Round 8
// baseline (561.556 us; speedup 1.0000x reference)
//
#include <hip/hip_runtime.h>
#include <stdint.h>

#define NB 8192      // tokens
#define ND 2048      // input dim
#define NO 2048      // output dim
#define NE 8         // experts
#define BK 64        // K-tile in bf16 elems (128 B)
#define NT (ND / BK) // 32 K-tiles
#define BM 256
#define BN 256
#define MAXW 72      // max active (e,mt) tiles: sum ceil(cnt_e/256) <= 64+7=71

typedef __bf16 bf16x8 __attribute__((ext_vector_type(8)));
typedef float floatx4 __attribute__((ext_vector_type(4)));

__device__ __forceinline__ unsigned short f2bf(float f) {
    union { float f; uint32_t u; } v; v.f = f;
    uint32_t u = v.u;
    return (unsigned short)((u + 0x7FFFu + ((u >> 16) & 1u)) >> 16);  // RNE
}

// Convert expert_w fp32 -> bf16 AND zero the output (atomic-accumulate base).
__global__ __launch_bounds__(256) void cvt_zero_kernel(
        const float* __restrict__ w, unsigned short* __restrict__ ob,
        float* __restrict__ out) {
    const int n4W = NE * NO * ND / 4;
    const int n4O = NB * NO / 4;
    int i = blockIdx.x * blockDim.x + threadIdx.x;
    int stride = gridDim.x * blockDim.x;
    for (; i < n4W + n4O; i += stride) {
        if (i < n4W) {
            float4 v = ((const float4*)w)[i];
            ushort4 o;
            o.x = f2bf(v.x); o.y = f2bf(v.y); o.z = f2bf(v.z); o.w = f2bf(v.w);
            ((ushort4*)ob)[i] = o;
        } else {
            float4 z = {0.f, 0.f, 0.f, 0.f};
            ((float4*)out)[i - n4W] = z;
        }
    }
}

// Phase 1: one wave per token; fp32 logits, top-2 + softmax, and x->bf16.
__global__ __launch_bounds__(256) void router_topk_kernel(const float* __restrict__ x,
        const float* __restrict__ rw, const float* __restrict__ rb,
        unsigned short* __restrict__ xbf,
        int* __restrict__ i0a, int* __restrict__ i1a,
        float* __restrict__ w0a, float* __restrict__ w1a,
        int* __restrict__ cnt) {
    if (blockIdx.x == 0 && threadIdx.x < NE) cnt[threadIdx.x] = 0;
    const int wave = threadIdx.x >> 6;
    const int lane = threadIdx.x & 63;
    const int t = blockIdx.x * 4 + wave;
    const float4* xp = (const float4*)(x + (size_t)t * ND);
    const float4* rp = (const float4*)rw;
    ushort4* xo = (ushort4*)(xbf + (size_t)t * ND);
    float acc[NE];
#pragma unroll
    for (int e = 0; e < NE; e++) acc[e] = 0.f;
#pragma unroll
    for (int i = 0; i < ND / 256; i++) {
        int idx = i * 64 + lane;
        float4 xv = xp[idx];
        ushort4 o;
        o.x = f2bf(xv.x); o.y = f2bf(xv.y); o.z = f2bf(xv.z); o.w = f2bf(xv.w);
        xo[idx] = o;
#pragma unroll
        for (int e = 0; e < NE; e++) {
            float4 rv = rp[(size_t)e * (ND / 4) + idx];
            acc[e] += xv.x * rv.x + xv.y * rv.y + xv.z * rv.z + xv.w * rv.w;
        }
    }
#pragma unroll
    for (int e = 0; e < NE; e++) {
        float v = acc[e];
#pragma unroll
        for (int s = 32; s > 0; s >>= 1) v += __shfl_xor(v, s, 64);
        acc[e] = v;
    }
    if (lane == 0) {
        float lg[NE];
#pragma unroll
        for (int e = 0; e < NE; e++) lg[e] = acc[e] + rb[e];
        int i0 = 0; float v0 = lg[0];
#pragma unroll
        for (int e = 1; e < NE; e++) if (lg[e] > v0) { v0 = lg[e]; i0 = e; }
        int i1 = -1; float v1 = -3.4e38f;
#pragma unroll
        for (int e = 0; e < NE; e++) if (e != i0 && lg[e] > v1) { v1 = lg[e]; i1 = e; }
        float ex = expf(v1 - v0);
        float inv = 1.f / (1.f + ex);
        i0a[t] = i0; i1a[t] = i1;
        w0a[t] = inv; w1a[t] = ex * inv;
    }
}

// Phase 2: ballot-compaction into ONE combined list per expert.
__global__ __launch_bounds__(256) void compact_kernel(
        const int* __restrict__ i0a, const int* __restrict__ i1a,
        const float* __restrict__ w0a, const float* __restrict__ w1a,
        int* __restrict__ cnt, int* __restrict__ tok, float* __restrict__ wl) {
    const int lane = threadIdx.x & 63;
    const int gw = (blockIdx.x * 256 + threadIdx.x) >> 6;
    const int t = gw * 64 + lane;
#pragma unroll
    for (int which = 0; which < 2; which++) {
        int sel   = which ? i1a[t] : i0a[t];
        float w   = which ? w1a[t] : w0a[t];
        unsigned long long m[NE];
#pragma unroll
        for (int e = 0; e < NE; e++) m[e] = __ballot(sel == e);
        int slot = __popcll(m[sel] & ((1ull << lane) - 1ull));
        int base = 0;
        if (lane < NE) base = atomicAdd(&cnt[lane], (int)__popcll(m[lane]));
        base = __shfl(base, sel, 64);
        tok[sel * NB + base + slot] = t;
        wl[sel * NB + base + slot]  = w;
    }
}

#define GLL16(g, l) __builtin_amdgcn_global_load_lds( \
    (const __attribute__((address_space(1))) void*)(g), \
    (__attribute__((address_space(3))) void*)(l), 16, 0, 0)

#define BAR __builtin_amdgcn_s_barrier()
#define WAITL asm volatile("s_waitcnt lgkmcnt(0)" ::: "memory")

#define LDA(HALFPTR) do {                                                   \
    const char* _p = (const char*)(HALFPTR);                                \
    _Pragma("unroll") for (int mi = 0; mi < 4; mi++)                        \
        _Pragma("unroll") for (int kk = 0; kk < 2; kk++)                    \
            af[mi][kk] = *(const bf16x8*)(_p + offA[mi][kk]);               \
} while (0)

#define LDB(HALFPTR) do {                                                   \
    const char* _p = (const char*)(HALFPTR);                                \
    _Pragma("unroll") for (int nj = 0; nj < 2; nj++)                        \
        _Pragma("unroll") for (int kk = 0; kk < 2; kk++)                    \
            bfr[nj][kk] = *(const bf16x8*)(_p + offB[nj][kk]);              \
} while (0)

#define MMAC(MH, NH) do {                                                   \
    __builtin_amdgcn_s_setprio(1);                                          \
    _Pragma("unroll") for (int kk = 0; kk < 2; kk++)                        \
        _Pragma("unroll") for (int mi = 0; mi < 4; mi++)                    \
            _Pragma("unroll") for (int nj = 0; nj < 2; nj++)                \
                acc[(MH)*4+mi][(NH)*2+nj] =                                 \
                    __builtin_amdgcn_mfma_f32_16x16x32_bf16(                \
                        af[mi][kk], bfr[nj][kk],                            \
                        acc[(MH)*4+mi][(NH)*2+nj], 0, 0, 0);                \
    __builtin_amdgcn_s_setprio(0);                                          \
} while (0)

#define STG_A(D, H, KT) do { if ((KT) < NT) {                               \
    GLL16(bA[H][0] + (size_t)(KT) * 128, (char*)sA[D][H] + tid * 16);       \
    GLL16(bA[H][1] + (size_t)(KT) * 128, (char*)sA[D][H] + 8192 + tid * 16);\
} } while (0)
#define STG_B(D, H, KT) do { if ((KT) < NT) {                               \
    GLL16(bB[H][0] + (size_t)(KT) * 128, (char*)sB[D][H] + tid * 16);       \
    GLL16(bB[H][1] + (size_t)(KT) * 128, (char*)sB[D][H] + 8192 + tid * 16);\
} } while (0)

// 256x256 tile, BK=64, 512 threads (8 waves). 8-phase schedule (T3+T4+T2+T5).
// Resubmit of R7 (bench infra failed; full re-audit found no fault):
// 1) IN-KERNEL WORK-LIST: grid = 8 nt x 72 widx; block scalar-decodes
//    widx -> (e, mt) from ceil(cnt_e/256) prefix (sum <= 71 provably).
//    Zero wasted dispatches, balanced; nt = bid&7 keeps T1 XCD residue.
// 2) DEPTH-3 PIPELINE: prologue stages 7 half-tiles; each phase stages the
//    half freed exactly one phase earlier; vmcnt(6) checkpoints at P4/P8
//    (3 half-tiles = 6 loads in flight; m201's N = 2x3 = 6). Ledger audited:
//    at each checkpoint the retired-8 are exactly the tile about to be read;
//    remaining-6 = next odd/even tile's A0,B1,A1 (loop invariant).
__global__ __launch_bounds__(512, 2) void moe_gemm_kernel(
        const unsigned short* __restrict__ xbf, const unsigned short* __restrict__ wbf,
        const float* __restrict__ eb, const int* __restrict__ cntArr,
        const int* __restrict__ listTok, const float* __restrict__ listW,
        float* __restrict__ out) {
    __shared__ unsigned short sA[2][2][128 * 64];
    __shared__ unsigned short sB[2][2][128 * 64];

    const int bid = blockIdx.x;
    const int nt = bid & 7;          // XCD residue: same (e,nt) panel -> same XCD
    const int widx = bid >> 3;       // 0..71
    int e = 0, mt = 0;
    {
        int acc0 = 0; int found = 0;
#pragma unroll
        for (int k = 0; k < NE; k++) {
            int nmt = (cntArr[k] + BM - 1) >> 8;
            if (!found && widx < acc0 + nmt) { e = k; mt = widx - acc0; found = 1; }
            acc0 += nmt;
        }
        if (!found) return;          // beyond total active tiles (uniform; pre-barrier)
    }
    const int cnt = cntArr[e];
    const int tid = threadIdx.x;

    const int prow0 = tid >> 3;
    const int prow1 = 64 + (tid >> 3);
    const int scol  = ((tid & 7) * 16) ^ (((tid >> 3) & 7) << 4);
    const char* bA[2][2]; const char* bB[2][2];
#pragma unroll
    for (int h = 0; h < 2; h++) {
        int g0 = mt * BM + h * 128 + prow0;
        int g1 = mt * BM + h * 128 + prow1;
        int tk0 = (g0 < cnt) ? listTok[e * NB + g0] : 0;
        int tk1 = (g1 < cnt) ? listTok[e * NB + g1] : 0;
        bA[h][0] = (const char*)xbf + (size_t)tk0 * (ND * 2) + scol;
        bA[h][1] = (const char*)xbf + (size_t)tk1 * (ND * 2) + scol;
        bB[h][0] = (const char*)wbf + ((size_t)e * NO + (size_t)nt * BN + h * 128 + prow0) * (ND * 2) + scol;
        bB[h][1] = (const char*)wbf + ((size_t)e * NO + (size_t)nt * BN + h * 128 + prow1) * (ND * 2) + scol;
    }

    const int wave = tid >> 6, lane = tid & 63;
    const int wm2 = wave >> 2;
    const int wn2 = wave & 3;
    const int lr = lane & 15, lq = lane >> 4;
    const int xorv = (lr & 7) << 4;
    int offA[4][2], offB[2][2];
#pragma unroll
    for (int mi = 0; mi < 4; mi++)
#pragma unroll
        for (int kk = 0; kk < 2; kk++)
            offA[mi][kk] = (wm2 * 64 + mi * 16 + lr) * 128 + ((kk * 64 + lq * 16) ^ xorv);
#pragma unroll
    for (int nj = 0; nj < 2; nj++)
#pragma unroll
        for (int kk = 0; kk < 2; kk++)
            offB[nj][kk] = (wn2 * 32 + nj * 16 + lr) * 128 + ((kk * 64 + lq * 16) ^ xorv);

    bf16x8 af[4][2], bfr[2][2];
    floatx4 acc[8][4];
#pragma unroll
    for (int i = 0; i < 8; i++)
#pragma unroll
        for (int j = 0; j < 4; j++) acc[i][j] = (floatx4){0.f, 0.f, 0.f, 0.f};

    // prologue: tile 0 complete (4 halves FIRST: vmcnt(6) retires exactly
    // these 8 loads) + tile 1's A0, A1, B1 (B0 staged at P1).
    STG_A(0, 0, 0); STG_A(0, 1, 0); STG_B(0, 0, 0); STG_B(0, 1, 0);
    STG_A(1, 0, 1); STG_A(1, 1, 1); STG_B(1, 1, 1);
    asm volatile("s_waitcnt vmcnt(6)" ::: "memory");
    BAR;

#pragma unroll 1
    for (int i = 0; i < NT / 2; i++) {
        const int t1 = 2 * i + 1, t2 = 2 * i + 2, t3 = 2 * i + 3;
        // P1: Q(0,0) d0 | stage B0(t1)->d1.B0 (freed prev P8)
        LDA(sA[0][0]); LDB(sB[0][0]);
        STG_B(1, 0, t1);
        BAR; MMAC(0, 0); WAITL; BAR;
        // P2: Q(0,1) d0 | stage A0(t2)->d0.A0 (freed P1)
        LDB(sB[0][1]);
        STG_A(0, 0, t2);
        BAR; MMAC(0, 1); WAITL; BAR;
        // P3: Q(1,1) d0 | stage B1(t2)->d0.B1 (freed P2)
        LDA(sA[0][1]);
        STG_B(0, 1, t2);
        BAR; MMAC(1, 1); WAITL; BAR;
        // P4: Q(1,0) d0 | stage A1(t2)->d0.A1 (freed P3) | checkpoint
        LDB(sB[0][0]);
        STG_A(0, 1, t2);
        BAR; MMAC(1, 0); WAITL;
        if (t2 < NT) { asm volatile("s_waitcnt vmcnt(6)" ::: "memory"); }
        else         { asm volatile("s_waitcnt vmcnt(0)" ::: "memory"); }
        BAR;
        // P5: Q(0,0) d1 | stage B0(t2)->d0.B0 (freed P4)
        LDA(sA[1][0]); LDB(sB[1][0]);
        STG_B(0, 0, t2);
        BAR; MMAC(0, 0); WAITL; BAR;
        // P6: Q(0,1) d1 | stage A0(t3)->d1.A0 (freed P5)
        LDB(sB[1][1]);
        STG_A(1, 0, t3);
        BAR; MMAC(0, 1); WAITL; BAR;
        // P7: Q(1,1) d1 | stage B1(t3)->d1.B1 (freed P6)
        LDA(sA[1][1]);
        STG_B(1, 1, t3);
        BAR; MMAC(1, 1); WAITL; BAR;
        // P8: Q(1,0) d1 | stage A1(t3)->d1.A1 (freed P7) | checkpoint
        LDB(sB[1][0]);
        STG_A(1, 1, t3);
        BAR; MMAC(1, 0); WAITL;
        if (t3 < NT) { asm volatile("s_waitcnt vmcnt(6)" ::: "memory"); }
        else         { asm volatile("s_waitcnt vmcnt(0)" ::: "memory"); }
        BAR;
    }

    // epilogue: C/D layout col=lane&15, row=(lane>>4)*4+reg; atomic combine
    float ebv[4];
#pragma unroll
    for (int nh = 0; nh < 2; nh++)
#pragma unroll
        for (int nj = 0; nj < 2; nj++)
            ebv[nh * 2 + nj] = eb[(size_t)e * NO + nt * BN + nh * 128 + wn2 * 32 + nj * 16 + lr];
#pragma unroll
    for (int mh = 0; mh < 2; mh++)
#pragma unroll
    for (int mi = 0; mi < 4; mi++)
#pragma unroll
    for (int r = 0; r < 4; r++) {
        int gr = mt * BM + mh * 128 + wm2 * 64 + mi * 16 + lq * 4 + r;
        if (gr < cnt) {
            int tk   = listTok[e * NB + gr];
            float wg = listW[e * NB + gr];
            float* op = out + (size_t)tk * NO + nt * BN + lr;
#pragma unroll
            for (int nh = 0; nh < 2; nh++)
#pragma unroll
            for (int nj = 0; nj < 2; nj++)
                atomicAdd(op + nh * 128 + wn2 * 32 + nj * 16,
                          wg * (acc[mh * 4 + mi][nh * 2 + nj][r] + ebv[nh * 2 + nj]));
        }
    }
}

extern "C" void kernel_launch(void* const* d_in, const int* in_sizes, int n_in,
                              void* d_out, int out_size, void* d_ws, size_t ws_size,
                              hipStream_t stream) {
    const float* x        = (const float*)d_in[0];
    const float* router_w = (const float*)d_in[1];
    const float* router_b = (const float*)d_in[2];
    const float* expert_w = (const float*)d_in[3];
    const float* expert_b = (const float*)d_in[4];
    float* out = (float*)d_out;
    char* ws = (char*)d_ws;

    unsigned short* xbf = (unsigned short*)ws;                 // 33,554,432 B
    unsigned short* wbf = (unsigned short*)(ws + 33554432);    // 67,108,864 B
    size_t o = 100663296;
    int*   tokL = (int*)(ws + o);   o += NE * NB * 4;
    float* wL   = (float*)(ws + o); o += NE * NB * 4;
    int*   i0a  = (int*)(ws + o);   o += NB * 4;
    int*   i1a  = (int*)(ws + o);   o += NB * 4;
    float* w0a  = (float*)(ws + o); o += NB * 4;
    float* w1a  = (float*)(ws + o); o += NB * 4;
    int*   cnt  = (int*)(ws + o);   o += 128;

    router_topk_kernel<<<NB / 4, 256, 0, stream>>>(x, router_w, router_b, xbf,
                                                   i0a, i1a, w0a, w1a, cnt);
    cvt_zero_kernel<<<2048, 256, 0, stream>>>(expert_w, wbf, out);
    compact_kernel<<<NB / 64 / 4, 256, 0, stream>>>(i0a, i1a, w0a, w1a, cnt, tokL, wL);
    moe_gemm_kernel<<<MAXW * 8, 512, 0, stream>>>(
        xbf, wbf, expert_b, cnt, tokL, wL, out);
}

// Round 9
// 553.227 us; speedup vs baseline: 1.0151x; 1.0151x over previous
//
#include <hip/hip_runtime.h>
#include <stdint.h>

#define NB 8192      // tokens
#define ND 2048      // input dim
#define NO 2048      // output dim
#define NE 8         // experts
#define BK 64        // K-tile in bf16 elems (128 B)
#define NT (ND / BK) // 32 K-tiles
#define BM 256
#define BN 256
#define MAXW 40      // per pass: sum ceil(cnt_e/256) <= 8192/256 + 7 = 39

typedef __bf16 bf16x8 __attribute__((ext_vector_type(8)));
typedef float floatx4 __attribute__((ext_vector_type(4)));

__device__ __forceinline__ unsigned short f2bf(float f) {
    union { float f; uint32_t u; } v; v.f = f;
    uint32_t u = v.u;
    return (unsigned short)((u + 0x7FFFu + ((u >> 16) & 1u)) >> 16);  // RNE
}

// Convert expert_w fp32 -> bf16. (out-zeroing no longer needed: pass A of the
// GEMM plain-writes every token row.)
__global__ __launch_bounds__(256) void cvt_kernel(
        const float* __restrict__ w, unsigned short* __restrict__ ob) {
    const int n4W = NE * NO * ND / 4;
    int i = blockIdx.x * blockDim.x + threadIdx.x;
    int stride = gridDim.x * blockDim.x;
    for (; i < n4W; i += stride) {
        float4 v = ((const float4*)w)[i];
        ushort4 o;
        o.x = f2bf(v.x); o.y = f2bf(v.y); o.z = f2bf(v.z); o.w = f2bf(v.w);
        ((ushort4*)ob)[i] = o;
    }
}

// Phase 1: one wave per token; fp32 logits, top-2 + softmax, and x->bf16.
// Block 0 zeroes both compaction counter arrays (16 ints).
__global__ __launch_bounds__(256) void router_topk_kernel(const float* __restrict__ x,
        const float* __restrict__ rw, const float* __restrict__ rb,
        unsigned short* __restrict__ xbf,
        int* __restrict__ i0a, int* __restrict__ i1a,
        float* __restrict__ w0a, float* __restrict__ w1a,
        int* __restrict__ cnt) {
    if (blockIdx.x == 0 && threadIdx.x < 2 * NE) cnt[threadIdx.x] = 0;
    const int wave = threadIdx.x >> 6;
    const int lane = threadIdx.x & 63;
    const int t = blockIdx.x * 4 + wave;
    const float4* xp = (const float4*)(x + (size_t)t * ND);
    const float4* rp = (const float4*)rw;
    ushort4* xo = (ushort4*)(xbf + (size_t)t * ND);
    float acc[NE];
#pragma unroll
    for (int e = 0; e < NE; e++) acc[e] = 0.f;
#pragma unroll
    for (int i = 0; i < ND / 256; i++) {
        int idx = i * 64 + lane;
        float4 xv = xp[idx];
        ushort4 o;
        o.x = f2bf(xv.x); o.y = f2bf(xv.y); o.z = f2bf(xv.z); o.w = f2bf(xv.w);
        xo[idx] = o;
#pragma unroll
        for (int e = 0; e < NE; e++) {
            float4 rv = rp[(size_t)e * (ND / 4) + idx];
            acc[e] += xv.x * rv.x + xv.y * rv.y + xv.z * rv.z + xv.w * rv.w;
        }
    }
#pragma unroll
    for (int e = 0; e < NE; e++) {
        float v = acc[e];
#pragma unroll
        for (int s = 32; s > 0; s >>= 1) v += __shfl_xor(v, s, 64);
        acc[e] = v;
    }
    if (lane == 0) {
        float lg[NE];
#pragma unroll
        for (int e = 0; e < NE; e++) lg[e] = acc[e] + rb[e];
        int i0 = 0; float v0 = lg[0];
#pragma unroll
        for (int e = 1; e < NE; e++) if (lg[e] > v0) { v0 = lg[e]; i0 = e; }
        int i1 = -1; float v1 = -3.4e38f;
#pragma unroll
        for (int e = 0; e < NE; e++) if (e != i0 && lg[e] > v1) { v1 = lg[e]; i1 = e; }
        float ex = expf(v1 - v0);
        float inv = 1.f / (1.f + ex);
        i0a[t] = i0; i1a[t] = i1;
        w0a[t] = inv; w1a[t] = ex * inv;
    }
}

// Phase 2: ballot-compaction into TWO per-expert lists (top-1 list A covers
// every token exactly once; top-2 list B likewise). Rows within one list are
// distinct tokens -> each GEMM pass's output rows are disjoint (no atomics).
__global__ __launch_bounds__(256) void compact_kernel(
        const int* __restrict__ i0a, const int* __restrict__ i1a,
        const float* __restrict__ w0a, const float* __restrict__ w1a,
        int* __restrict__ cntA, int* __restrict__ cntB,
        int* __restrict__ tokA, float* __restrict__ wA,
        int* __restrict__ tokB, float* __restrict__ wB) {
    const int lane = threadIdx.x & 63;
    const int gw = (blockIdx.x * 256 + threadIdx.x) >> 6;
    const int t = gw * 64 + lane;
#pragma unroll
    for (int which = 0; which < 2; which++) {
        int sel   = which ? i1a[t] : i0a[t];
        float w   = which ? w1a[t] : w0a[t];
        int* cnt  = which ? cntB : cntA;
        int* tok  = which ? tokB : tokA;
        float* wl = which ? wB : wA;
        unsigned long long m[NE];
#pragma unroll
        for (int e = 0; e < NE; e++) m[e] = __ballot(sel == e);
        int slot = __popcll(m[sel] & ((1ull << lane) - 1ull));
        int base = 0;
        if (lane < NE) base = atomicAdd(&cnt[lane], (int)__popcll(m[lane]));
        base = __shfl(base, sel, 64);
        tok[sel * NB + base + slot] = t;
        wl[sel * NB + base + slot]  = w;
    }
}

#define GLL16(g, l) __builtin_amdgcn_global_load_lds( \
    (const __attribute__((address_space(1))) void*)(g), \
    (__attribute__((address_space(3))) void*)(l), 16, 0, 0)

#define BAR __builtin_amdgcn_s_barrier()
#define WAITL asm volatile("s_waitcnt lgkmcnt(0)" ::: "memory")

#define LDA(HALFPTR) do {                                                   \
    const char* _p = (const char*)(HALFPTR);                                \
    _Pragma("unroll") for (int mi = 0; mi < 4; mi++)                        \
        _Pragma("unroll") for (int kk = 0; kk < 2; kk++)                    \
            af[mi][kk] = *(const bf16x8*)(_p + offA[mi][kk]);               \
} while (0)

#define LDB(HALFPTR) do {                                                   \
    const char* _p = (const char*)(HALFPTR);                                \
    _Pragma("unroll") for (int nj = 0; nj < 2; nj++)                        \
        _Pragma("unroll") for (int kk = 0; kk < 2; kk++)                    \
            bfr[nj][kk] = *(const bf16x8*)(_p + offB[nj][kk]);              \
} while (0)

#define MMAC(MH, NH) do {                                                   \
    __builtin_amdgcn_s_setprio(1);                                          \
    _Pragma("unroll") for (int kk = 0; kk < 2; kk++)                        \
        _Pragma("unroll") for (int mi = 0; mi < 4; mi++)                    \
            _Pragma("unroll") for (int nj = 0; nj < 2; nj++)                \
                acc[(MH)*4+mi][(NH)*2+nj] =                                 \
                    __builtin_amdgcn_mfma_f32_16x16x32_bf16(                \
                        af[mi][kk], bfr[nj][kk],                            \
                        acc[(MH)*4+mi][(NH)*2+nj], 0, 0, 0);                \
    __builtin_amdgcn_s_setprio(0);                                          \
} while (0)

#define STG_A(D, H, KT) do { if ((KT) < NT) {                               \
    GLL16(bA[H][0] + (size_t)(KT) * 128, (char*)sA[D][H] + tid * 16);       \
    GLL16(bA[H][1] + (size_t)(KT) * 128, (char*)sA[D][H] + 8192 + tid * 16);\
} } while (0)
#define STG_B(D, H, KT) do { if ((KT) < NT) {                               \
    GLL16(bB[H][0] + (size_t)(KT) * 128, (char*)sB[D][H] + tid * 16);       \
    GLL16(bB[H][1] + (size_t)(KT) * 128, (char*)sB[D][H] + 8192 + tid * 16);\
} } while (0)

// 256x256 tile, BK=64, 512 threads (8 waves). 8-phase schedule (T3+T4+T2+T5),
// work-list decode + depth-3 vmcnt(6) ledger — byte-identical K-loop to R8.
// R9 change: ATOMIC-FREE EPILOGUE via two passes. ACCUM=false: plain store
// w*(acc+bias) (pass A = top-1 list, covers every token once -> also replaces
// the out-zeroing memset). ACCUM=true: read-modify-write add (pass B = top-2
// list; rows disjoint within the pass; stream order makes pass A visible).
// Theory: the 37M-atomic epilogue serialized ~100+ us at L2 while the MFMA
// pipe idled (MfmaUtil 21% == 60us MFMA / 284us; no other pipe >21%).
template <bool ACCUM>
__global__ __launch_bounds__(512, 2) void moe_gemm_kernel(
        const unsigned short* __restrict__ xbf, const unsigned short* __restrict__ wbf,
        const float* __restrict__ eb, const int* __restrict__ cntArr,
        const int* __restrict__ listTok, const float* __restrict__ listW,
        float* __restrict__ out) {
    __shared__ unsigned short sA[2][2][128 * 64];
    __shared__ unsigned short sB[2][2][128 * 64];

    const int bid = blockIdx.x;
    const int nt = bid & 7;          // XCD residue: same (e,nt) panel -> same XCD
    const int widx = bid >> 3;       // 0..MAXW-1
    int e = 0, mt = 0;
    {
        int acc0 = 0; int found = 0;
#pragma unroll
        for (int k = 0; k < NE; k++) {
            int nmt = (cntArr[k] + BM - 1) >> 8;
            if (!found && widx < acc0 + nmt) { e = k; mt = widx - acc0; found = 1; }
            acc0 += nmt;
        }
        if (!found) return;          // uniform, pre-barrier
    }
    const int cnt = cntArr[e];
    const int tid = threadIdx.x;

    const int prow0 = tid >> 3;
    const int prow1 = 64 + (tid >> 3);
    const int scol  = ((tid & 7) * 16) ^ (((tid >> 3) & 7) << 4);
    const char* bA[2][2]; const char* bB[2][2];
#pragma unroll
    for (int h = 0; h < 2; h++) {
        int g0 = mt * BM + h * 128 + prow0;
        int g1 = mt * BM + h * 128 + prow1;
        int tk0 = (g0 < cnt) ? listTok[e * NB + g0] : 0;
        int tk1 = (g1 < cnt) ? listTok[e * NB + g1] : 0;
        bA[h][0] = (const char*)xbf + (size_t)tk0 * (ND * 2) + scol;
        bA[h][1] = (const char*)xbf + (size_t)tk1 * (ND * 2) + scol;
        bB[h][0] = (const char*)wbf + ((size_t)e * NO + (size_t)nt * BN + h * 128 + prow0) * (ND * 2) + scol;
        bB[h][1] = (const char*)wbf + ((size_t)e * NO + (size_t)nt * BN + h * 128 + prow1) * (ND * 2) + scol;
    }

    const int wave = tid >> 6, lane = tid & 63;
    const int wm2 = wave >> 2;
    const int wn2 = wave & 3;
    const int lr = lane & 15, lq = lane >> 4;
    const int xorv = (lr & 7) << 4;
    int offA[4][2], offB[2][2];
#pragma unroll
    for (int mi = 0; mi < 4; mi++)
#pragma unroll
        for (int kk = 0; kk < 2; kk++)
            offA[mi][kk] = (wm2 * 64 + mi * 16 + lr) * 128 + ((kk * 64 + lq * 16) ^ xorv);
#pragma unroll
    for (int nj = 0; nj < 2; nj++)
#pragma unroll
        for (int kk = 0; kk < 2; kk++)
            offB[nj][kk] = (wn2 * 32 + nj * 16 + lr) * 128 + ((kk * 64 + lq * 16) ^ xorv);

    bf16x8 af[4][2], bfr[2][2];
    floatx4 acc[8][4];
#pragma unroll
    for (int i = 0; i < 8; i++)
#pragma unroll
        for (int j = 0; j < 4; j++) acc[i][j] = (floatx4){0.f, 0.f, 0.f, 0.f};

    // prologue: tile 0 complete (4 halves FIRST: vmcnt(6) retires exactly
    // these 8 loads) + tile 1's A0, A1, B1 (B0 staged at P1).
    STG_A(0, 0, 0); STG_A(0, 1, 0); STG_B(0, 0, 0); STG_B(0, 1, 0);
    STG_A(1, 0, 1); STG_A(1, 1, 1); STG_B(1, 1, 1);
    asm volatile("s_waitcnt vmcnt(6)" ::: "memory");
    BAR;

#pragma unroll 1
    for (int i = 0; i < NT / 2; i++) {
        const int t1 = 2 * i + 1, t2 = 2 * i + 2, t3 = 2 * i + 3;
        // P1: Q(0,0) d0 | stage B0(t1)->d1.B0 (freed prev P8)
        LDA(sA[0][0]); LDB(sB[0][0]);
        STG_B(1, 0, t1);
        BAR; MMAC(0, 0); WAITL; BAR;
        // P2: Q(0,1) d0 | stage A0(t2)->d0.A0 (freed P1)
        LDB(sB[0][1]);
        STG_A(0, 0, t2);
        BAR; MMAC(0, 1); WAITL; BAR;
        // P3: Q(1,1) d0 | stage B1(t2)->d0.B1 (freed P2)
        LDA(sA[0][1]);
        STG_B(0, 1, t2);
        BAR; MMAC(1, 1); WAITL; BAR;
        // P4: Q(1,0) d0 | stage A1(t2)->d0.A1 (freed P3) | checkpoint
        LDB(sB[0][0]);
        STG_A(0, 1, t2);
        BAR; MMAC(1, 0); WAITL;
        if (t2 < NT) { asm volatile("s_waitcnt vmcnt(6)" ::: "memory"); }
        else         { asm volatile("s_waitcnt vmcnt(0)" ::: "memory"); }
        BAR;
        // P5: Q(0,0) d1 | stage B0(t2)->d0.B0 (freed P4)
        LDA(sA[1][0]); LDB(sB[1][0]);
        STG_B(0, 0, t2);
        BAR; MMAC(0, 0); WAITL; BAR;
        // P6: Q(0,1) d1 | stage A0(t3)->d1.A0 (freed P5)
        LDB(sB[1][1]);
        STG_A(1, 0, t3);
        BAR; MMAC(0, 1); WAITL; BAR;
        // P7: Q(1,1) d1 | stage B1(t3)->d1.B1 (freed P6)
        LDA(sA[1][1]);
        STG_B(1, 1, t3);
        BAR; MMAC(1, 1); WAITL; BAR;
        // P8: Q(1,0) d1 | stage A1(t3)->d1.A1 (freed P7) | checkpoint
        LDB(sB[1][0]);
        STG_A(1, 1, t3);
        BAR; MMAC(1, 0); WAITL;
        if (t3 < NT) { asm volatile("s_waitcnt vmcnt(6)" ::: "memory"); }
        else         { asm volatile("s_waitcnt vmcnt(0)" ::: "memory"); }
        BAR;
    }

    // epilogue: C/D layout col=lane&15, row=(lane>>4)*4+reg.
    // Pass A: plain store; pass B: read-modify-write. No atomics — rows
    // within one pass's list are distinct tokens.
    float ebv[4];
#pragma unroll
    for (int nh = 0; nh < 2; nh++)
#pragma unroll
        for (int nj = 0; nj < 2; nj++)
            ebv[nh * 2 + nj] = eb[(size_t)e * NO + nt * BN + nh * 128 + wn2 * 32 + nj * 16 + lr];
#pragma unroll
    for (int mh = 0; mh < 2; mh++)
#pragma unroll
    for (int mi = 0; mi < 4; mi++)
#pragma unroll
    for (int r = 0; r < 4; r++) {
        int gr = mt * BM + mh * 128 + wm2 * 64 + mi * 16 + lq * 4 + r;
        if (gr < cnt) {
            int tk   = listTok[e * NB + gr];
            float wg = listW[e * NB + gr];
            float* op = out + (size_t)tk * NO + nt * BN + lr;
#pragma unroll
            for (int nh = 0; nh < 2; nh++)
#pragma unroll
            for (int nj = 0; nj < 2; nj++) {
                float* p = op + nh * 128 + wn2 * 32 + nj * 16;
                float v = wg * (acc[mh * 4 + mi][nh * 2 + nj][r] + ebv[nh * 2 + nj]);
                if (ACCUM) v += *p;
                *p = v;
            }
        }
    }
}

extern "C" void kernel_launch(void* const* d_in, const int* in_sizes, int n_in,
                              void* d_out, int out_size, void* d_ws, size_t ws_size,
                              hipStream_t stream) {
    const float* x        = (const float*)d_in[0];
    const float* router_w = (const float*)d_in[1];
    const float* router_b = (const float*)d_in[2];
    const float* expert_w = (const float*)d_in[3];
    const float* expert_b = (const float*)d_in[4];
    float* out = (float*)d_out;
    char* ws = (char*)d_ws;

    unsigned short* xbf = (unsigned short*)ws;                 // 33,554,432 B
    unsigned short* wbf = (unsigned short*)(ws + 33554432);    // 67,108,864 B
    size_t o = 100663296;
    int*   tokA = (int*)(ws + o);   o += NE * NB * 4;
    float* wA   = (float*)(ws + o); o += NE * NB * 4;
    int*   tokB = (int*)(ws + o);   o += NE * NB * 4;
    float* wB   = (float*)(ws + o); o += NE * NB * 4;
    int*   i0a  = (int*)(ws + o);   o += NB * 4;
    int*   i1a  = (int*)(ws + o);   o += NB * 4;
    float* w0a  = (float*)(ws + o); o += NB * 4;
    float* w1a  = (float*)(ws + o); o += NB * 4;
    int*   cnt  = (int*)(ws + o);   o += 128;   // cntA = cnt, cntB = cnt+8
    int* cntA = cnt;
    int* cntB = cnt + 8;

    router_topk_kernel<<<NB / 4, 256, 0, stream>>>(x, router_w, router_b, xbf,
                                                   i0a, i1a, w0a, w1a, cnt);
    cvt_kernel<<<2048, 256, 0, stream>>>(expert_w, wbf);
    compact_kernel<<<NB / 64 / 4, 256, 0, stream>>>(i0a, i1a, w0a, w1a,
                                                    cntA, cntB, tokA, wA, tokB, wB);
    moe_gemm_kernel<false><<<MAXW * 8, 512, 0, stream>>>(
        xbf, wbf, expert_b, cntA, tokA, wA, out);
    moe_gemm_kernel<true><<<MAXW * 8, 512, 0, stream>>>(
        xbf, wbf, expert_b, cntB, tokB, wB, out);
}

// Round 10
// 541.611 us; speedup vs baseline: 1.0368x; 1.0214x over previous
//
#include <hip/hip_runtime.h>
#include <stdint.h>

#define NB 8192      // tokens
#define ND 2048      // input dim
#define NO 2048      // output dim
#define NE 8         // experts
#define BK 64        // K-tile in bf16 elems (128 B)
#define NT (ND / BK) // 32 K-tiles
#define BM 256
#define BN 256

typedef __bf16 bf16x8 __attribute__((ext_vector_type(8)));
typedef float floatx4 __attribute__((ext_vector_type(4)));

__device__ __forceinline__ unsigned short f2bf(float f) {
    union { float f; uint32_t u; } v; v.f = f;
    uint32_t u = v.u;
    return (unsigned short)((u + 0x7FFFu + ((u >> 16) & 1u)) >> 16);  // RNE
}

// Phase 1 (fused): blocks < NB/4 run the router (one wave per token, fp32
// logits, top-2 + softmax, x->bf16); blocks >= NB/4 grid-stride-convert
// expert_w fp32 -> bf16. Independent work, one dispatch, shared BW.
__global__ __launch_bounds__(256) void router_cvt_kernel(const float* __restrict__ x,
        const float* __restrict__ rw, const float* __restrict__ rb,
        unsigned short* __restrict__ xbf,
        const float* __restrict__ ew, unsigned short* __restrict__ wbf,
        int* __restrict__ i0a, int* __restrict__ i1a,
        float* __restrict__ w0a, float* __restrict__ w1a,
        int* __restrict__ cnt) {
    if (blockIdx.x >= NB / 4) {
        const int n4W = NE * NO * ND / 4;
        int i = (blockIdx.x - NB / 4) * 256 + threadIdx.x;
        const int stride = 2048 * 256;
        for (; i < n4W; i += stride) {
            float4 v = ((const float4*)ew)[i];
            ushort4 o;
            o.x = f2bf(v.x); o.y = f2bf(v.y); o.z = f2bf(v.z); o.w = f2bf(v.w);
            ((ushort4*)wbf)[i] = o;
        }
        return;
    }
    if (blockIdx.x == 0 && threadIdx.x < 2 * NE) cnt[threadIdx.x] = 0;
    const int wave = threadIdx.x >> 6;
    const int lane = threadIdx.x & 63;
    const int t = blockIdx.x * 4 + wave;
    const float4* xp = (const float4*)(x + (size_t)t * ND);
    const float4* rp = (const float4*)rw;
    ushort4* xo = (ushort4*)(xbf + (size_t)t * ND);
    float acc[NE];
#pragma unroll
    for (int e = 0; e < NE; e++) acc[e] = 0.f;
#pragma unroll
    for (int i = 0; i < ND / 256; i++) {
        int idx = i * 64 + lane;
        float4 xv = xp[idx];
        ushort4 o;
        o.x = f2bf(xv.x); o.y = f2bf(xv.y); o.z = f2bf(xv.z); o.w = f2bf(xv.w);
        xo[idx] = o;
#pragma unroll
        for (int e = 0; e < NE; e++) {
            float4 rv = rp[(size_t)e * (ND / 4) + idx];
            acc[e] += xv.x * rv.x + xv.y * rv.y + xv.z * rv.z + xv.w * rv.w;
        }
    }
#pragma unroll
    for (int e = 0; e < NE; e++) {
        float v = acc[e];
#pragma unroll
        for (int s = 32; s > 0; s >>= 1) v += __shfl_xor(v, s, 64);
        acc[e] = v;
    }
    if (lane == 0) {
        float lg[NE];
#pragma unroll
        for (int e = 0; e < NE; e++) lg[e] = acc[e] + rb[e];
        int i0 = 0; float v0 = lg[0];
#pragma unroll
        for (int e = 1; e < NE; e++) if (lg[e] > v0) { v0 = lg[e]; i0 = e; }
        int i1 = -1; float v1 = -3.4e38f;
#pragma unroll
        for (int e = 0; e < NE; e++) if (e != i0 && lg[e] > v1) { v1 = lg[e]; i1 = e; }
        float ex = expf(v1 - v0);
        float inv = 1.f / (1.f + ex);
        i0a[t] = i0; i1a[t] = i1;
        w0a[t] = inv; w1a[t] = ex * inv;
    }
}

// Phase 2: ballot-compaction into TWO per-expert lists (top-1 list A covers
// every token exactly once; top-2 list B likewise). Rows within one list are
// distinct tokens -> each GEMM pass's output rows are disjoint (no atomics).
__global__ __launch_bounds__(256) void compact_kernel(
        const int* __restrict__ i0a, const int* __restrict__ i1a,
        const float* __restrict__ w0a, const float* __restrict__ w1a,
        int* __restrict__ cntA, int* __restrict__ cntB,
        int* __restrict__ tokA, float* __restrict__ wA,
        int* __restrict__ tokB, float* __restrict__ wB) {
    const int lane = threadIdx.x & 63;
    const int gw = (blockIdx.x * 256 + threadIdx.x) >> 6;
    const int t = gw * 64 + lane;
#pragma unroll
    for (int which = 0; which < 2; which++) {
        int sel   = which ? i1a[t] : i0a[t];
        float w   = which ? w1a[t] : w0a[t];
        int* cnt  = which ? cntB : cntA;
        int* tok  = which ? tokB : tokA;
        float* wl = which ? wB : wA;
        unsigned long long m[NE];
#pragma unroll
        for (int e = 0; e < NE; e++) m[e] = __ballot(sel == e);
        int slot = __popcll(m[sel] & ((1ull << lane) - 1ull));
        int base = 0;
        if (lane < NE) base = atomicAdd(&cnt[lane], (int)__popcll(m[lane]));
        base = __shfl(base, sel, 64);
        tok[sel * NB + base + slot] = t;
        wl[sel * NB + base + slot]  = w;
    }
}

#define GLL16(g, l) __builtin_amdgcn_global_load_lds( \
    (const __attribute__((address_space(1))) void*)(g), \
    (__attribute__((address_space(3))) void*)(l), 16, 0, 0)

#define BAR __builtin_amdgcn_s_barrier()
#define WAITL asm volatile("s_waitcnt lgkmcnt(0)" ::: "memory")

#define LDA(HALFPTR) do {                                                   \
    const char* _p = (const char*)(HALFPTR);                                \
    _Pragma("unroll") for (int mi = 0; mi < 4; mi++)                        \
        _Pragma("unroll") for (int kk = 0; kk < 2; kk++)                    \
            af[mi][kk] = *(const bf16x8*)(_p + offA[mi][kk]);               \
} while (0)

#define LDB(HALFPTR) do {                                                   \
    const char* _p = (const char*)(HALFPTR);                                \
    _Pragma("unroll") for (int nj = 0; nj < 2; nj++)                        \
        _Pragma("unroll") for (int kk = 0; kk < 2; kk++)                    \
            bfr[nj][kk] = *(const bf16x8*)(_p + offB[nj][kk]);              \
} while (0)

#define MMAC(MH, NH) do {                                                   \
    __builtin_amdgcn_s_setprio(1);                                          \
    _Pragma("unroll") for (int kk = 0; kk < 2; kk++)                        \
        _Pragma("unroll") for (int mi = 0; mi < 4; mi++)                    \
            _Pragma("unroll") for (int nj = 0; nj < 2; nj++)                \
                acc[(MH)*4+mi][(NH)*2+nj] =                                 \
                    __builtin_amdgcn_mfma_f32_16x16x32_bf16(                \
                        af[mi][kk], bfr[nj][kk],                            \
                        acc[(MH)*4+mi][(NH)*2+nj], 0, 0, 0);                \
    __builtin_amdgcn_s_setprio(0);                                          \
} while (0)

#define STG_A(D, H, KT) do { if ((KT) < NT) {                               \
    GLL16(bA[H][0] + (size_t)(KT) * 128, (char*)sA[D][H] + tid * 16);       \
    GLL16(bA[H][1] + (size_t)(KT) * 128, (char*)sA[D][H] + 8192 + tid * 16);\
} } while (0)
#define STG_B(D, H, KT) do { if ((KT) < NT) {                               \
    GLL16(bB[H][0] + (size_t)(KT) * 128, (char*)sB[D][H] + tid * 16);       \
    GLL16(bB[H][1] + (size_t)(KT) * 128, (char*)sB[D][H] + 8192 + tid * 16);\
} } while (0)

// 256x256 tile, BK=64, 512 threads (8 waves). 8-phase schedule (T3+T4+T2+T5),
// depth-3 vmcnt(6) ledger — K-loop byte-identical to passing R9.
// R10 change: EXPERT-PER-XCD mapping. e = bid&7 -> default %8 round-robin
// puts expert e's entire GEMM (4 mt x 8 nt = 32 blocks = the XCD's 32 CUs)
// on ONE XCD. A rows (4MB) L2-reused 8x, B panel (8MB) L2-reused 4x; K-tile
// streaming window ~384KB << 4MB L2. Kills the 8x cross-XCD A duplication
// (R9: FETCH 197MB vs 96MB unique; fabric-bound at ~1.9 TB/s; staging pinned
// at 3.5 TB/s while m97's L2-resident staging does ~14 TB/s on this path).
template <bool ACCUM>
__global__ __launch_bounds__(512, 2) void moe_gemm_kernel(
        const unsigned short* __restrict__ xbf, const unsigned short* __restrict__ wbf,
        const float* __restrict__ eb, const int* __restrict__ cntArr,
        const int* __restrict__ listTok, const float* __restrict__ listW,
        float* __restrict__ out) {
    __shared__ unsigned short sA[2][2][128 * 64];
    __shared__ unsigned short sB[2][2][128 * 64];

    const int bid = blockIdx.x;
    const int e = bid & 7;           // expert == XCD (default %8 round-robin)
    const int j = bid >> 3;          // 0..255
    const int nt = j & 7;
    const int mt = j >> 3;           // 0..31
    const int cnt = cntArr[e];
    if (mt * BM >= cnt) return;      // uniform, pre-barrier
    const int tid = threadIdx.x;

    const int prow0 = tid >> 3;
    const int prow1 = 64 + (tid >> 3);
    const int scol  = ((tid & 7) * 16) ^ (((tid >> 3) & 7) << 4);
    const char* bA[2][2]; const char* bB[2][2];
#pragma unroll
    for (int h = 0; h < 2; h++) {
        int g0 = mt * BM + h * 128 + prow0;
        int g1 = mt * BM + h * 128 + prow1;
        int tk0 = (g0 < cnt) ? listTok[e * NB + g0] : 0;
        int tk1 = (g1 < cnt) ? listTok[e * NB + g1] : 0;
        bA[h][0] = (const char*)xbf + (size_t)tk0 * (ND * 2) + scol;
        bA[h][1] = (const char*)xbf + (size_t)tk1 * (ND * 2) + scol;
        bB[h][0] = (const char*)wbf + ((size_t)e * NO + (size_t)nt * BN + h * 128 + prow0) * (ND * 2) + scol;
        bB[h][1] = (const char*)wbf + ((size_t)e * NO + (size_t)nt * BN + h * 128 + prow1) * (ND * 2) + scol;
    }

    const int wave = tid >> 6, lane = tid & 63;
    const int wm2 = wave >> 2;
    const int wn2 = wave & 3;
    const int lr = lane & 15, lq = lane >> 4;
    const int xorv = (lr & 7) << 4;
    int offA[4][2], offB[2][2];
#pragma unroll
    for (int mi = 0; mi < 4; mi++)
#pragma unroll
        for (int kk = 0; kk < 2; kk++)
            offA[mi][kk] = (wm2 * 64 + mi * 16 + lr) * 128 + ((kk * 64 + lq * 16) ^ xorv);
#pragma unroll
    for (int nj = 0; nj < 2; nj++)
#pragma unroll
        for (int kk = 0; kk < 2; kk++)
            offB[nj][kk] = (wn2 * 32 + nj * 16 + lr) * 128 + ((kk * 64 + lq * 16) ^ xorv);

    bf16x8 af[4][2], bfr[2][2];
    floatx4 acc[8][4];
#pragma unroll
    for (int i = 0; i < 8; i++)
#pragma unroll
        for (int j2 = 0; j2 < 4; j2++) acc[i][j2] = (floatx4){0.f, 0.f, 0.f, 0.f};

    // prologue: tile 0 complete (4 halves FIRST: vmcnt(6) retires exactly
    // these 8 loads) + tile 1's A0, A1, B1 (B0 staged at P1).
    STG_A(0, 0, 0); STG_A(0, 1, 0); STG_B(0, 0, 0); STG_B(0, 1, 0);
    STG_A(1, 0, 1); STG_A(1, 1, 1); STG_B(1, 1, 1);
    asm volatile("s_waitcnt vmcnt(6)" ::: "memory");
    BAR;

#pragma unroll 1
    for (int i = 0; i < NT / 2; i++) {
        const int t1 = 2 * i + 1, t2 = 2 * i + 2, t3 = 2 * i + 3;
        // P1: Q(0,0) d0 | stage B0(t1)->d1.B0 (freed prev P8)
        LDA(sA[0][0]); LDB(sB[0][0]);
        STG_B(1, 0, t1);
        BAR; MMAC(0, 0); WAITL; BAR;
        // P2: Q(0,1) d0 | stage A0(t2)->d0.A0 (freed P1)
        LDB(sB[0][1]);
        STG_A(0, 0, t2);
        BAR; MMAC(0, 1); WAITL; BAR;
        // P3: Q(1,1) d0 | stage B1(t2)->d0.B1 (freed P2)
        LDA(sA[0][1]);
        STG_B(0, 1, t2);
        BAR; MMAC(1, 1); WAITL; BAR;
        // P4: Q(1,0) d0 | stage A1(t2)->d0.A1 (freed P3) | checkpoint
        LDB(sB[0][0]);
        STG_A(0, 1, t2);
        BAR; MMAC(1, 0); WAITL;
        if (t2 < NT) { asm volatile("s_waitcnt vmcnt(6)" ::: "memory"); }
        else         { asm volatile("s_waitcnt vmcnt(0)" ::: "memory"); }
        BAR;
        // P5: Q(0,0) d1 | stage B0(t2)->d0.B0 (freed P4)
        LDA(sA[1][0]); LDB(sB[1][0]);
        STG_B(0, 0, t2);
        BAR; MMAC(0, 0); WAITL; BAR;
        // P6: Q(0,1) d1 | stage A0(t3)->d1.A0 (freed P5)
        LDB(sB[1][1]);
        STG_A(1, 0, t3);
        BAR; MMAC(0, 1); WAITL; BAR;
        // P7: Q(1,1) d1 | stage B1(t3)->d1.B1 (freed P6)
        LDA(sA[1][1]);
        STG_B(1, 1, t3);
        BAR; MMAC(1, 1); WAITL; BAR;
        // P8: Q(1,0) d1 | stage A1(t3)->d1.A1 (freed P7) | checkpoint
        LDB(sB[1][0]);
        STG_A(1, 1, t3);
        BAR; MMAC(1, 0); WAITL;
        if (t3 < NT) { asm volatile("s_waitcnt vmcnt(6)" ::: "memory"); }
        else         { asm volatile("s_waitcnt vmcnt(0)" ::: "memory"); }
        BAR;
    }

    // epilogue: C/D layout col=lane&15, row=(lane>>4)*4+reg.
    // Pass A: plain store (top-1 list covers every token once — replaces
    // out-zeroing); pass B: read-modify-write. Rows disjoint within a pass.
    float ebv[4];
#pragma unroll
    for (int nh = 0; nh < 2; nh++)
#pragma unroll
        for (int nj = 0; nj < 2; nj++)
            ebv[nh * 2 + nj] = eb[(size_t)e * NO + nt * BN + nh * 128 + wn2 * 32 + nj * 16 + lr];
#pragma unroll
    for (int mh = 0; mh < 2; mh++)
#pragma unroll
    for (int mi = 0; mi < 4; mi++)
#pragma unroll
    for (int r = 0; r < 4; r++) {
        int gr = mt * BM + mh * 128 + wm2 * 64 + mi * 16 + lq * 4 + r;
        if (gr < cnt) {
            int tk   = listTok[e * NB + gr];
            float wg = listW[e * NB + gr];
            float* op = out + (size_t)tk * NO + nt * BN + lr;
#pragma unroll
            for (int nh = 0; nh < 2; nh++)
#pragma unroll
            for (int nj = 0; nj < 2; nj++) {
                float* p = op + nh * 128 + wn2 * 32 + nj * 16;
                float v = wg * (acc[mh * 4 + mi][nh * 2 + nj][r] + ebv[nh * 2 + nj]);
                if (ACCUM) v += *p;
                *p = v;
            }
        }
    }
}

extern "C" void kernel_launch(void* const* d_in, const int* in_sizes, int n_in,
                              void* d_out, int out_size, void* d_ws, size_t ws_size,
                              hipStream_t stream) {
    const float* x        = (const float*)d_in[0];
    const float* router_w = (const float*)d_in[1];
    const float* router_b = (const float*)d_in[2];
    const float* expert_w = (const float*)d_in[3];
    const float* expert_b = (const float*)d_in[4];
    float* out = (float*)d_out;
    char* ws = (char*)d_ws;

    unsigned short* xbf = (unsigned short*)ws;                 // 33,554,432 B
    unsigned short* wbf = (unsigned short*)(ws + 33554432);    // 67,108,864 B
    size_t o = 100663296;
    int*   tokA = (int*)(ws + o);   o += NE * NB * 4;
    float* wA   = (float*)(ws + o); o += NE * NB * 4;
    int*   tokB = (int*)(ws + o);   o += NE * NB * 4;
    float* wB   = (float*)(ws + o); o += NE * NB * 4;
    int*   i0a  = (int*)(ws + o);   o += NB * 4;
    int*   i1a  = (int*)(ws + o);   o += NB * 4;
    float* w0a  = (float*)(ws + o); o += NB * 4;
    float* w1a  = (float*)(ws + o); o += NB * 4;
    int*   cnt  = (int*)(ws + o);   o += 128;   // cntA = cnt, cntB = cnt+8
    int* cntA = cnt;
    int* cntB = cnt + 8;

    router_cvt_kernel<<<NB / 4 + 2048, 256, 0, stream>>>(
        x, router_w, router_b, xbf, expert_w, wbf, i0a, i1a, w0a, w1a, cnt);
    compact_kernel<<<NB / 64 / 4, 256, 0, stream>>>(i0a, i1a, w0a, w1a,
                                                    cntA, cntB, tokA, wA, tokB, wB);
    moe_gemm_kernel<false><<<2048, 512, 0, stream>>>(
        xbf, wbf, expert_b, cntA, tokA, wA, out);
    moe_gemm_kernel<true><<<2048, 512, 0, stream>>>(
        xbf, wbf, expert_b, cntB, tokB, wB, out);
}